// Round 1
// baseline (519.807 us; speedup 1.0000x reference)
//
#include <hip/hip_runtime.h>
#include <hip/hip_bf16.h>
#include <cstdint>
#include <math.h>

// Problem constants
#define S_LEN   2048
#define B_SZ    2
#define D_MODEL 2048
#define NH      16
#define NKV     4
#define HD      128
#define ROWS    (S_LEN * B_SZ)          // 4096
#define NQKV    3072                    // NH*HD + 2*NKV*HD
#define SCALE   0.08838834764831845f    // 1/sqrt(HD)

typedef __attribute__((ext_vector_type(8))) short short8;   // 8 bf16 = 4 VGPRs
typedef __attribute__((ext_vector_type(4))) float f32x4;    // MFMA acc

__device__ __forceinline__ short f2bf(float f) {
  union { float f; unsigned u; } v; v.f = f;
  unsigned r = v.u + 0x7fffu + ((v.u >> 16) & 1u);   // RNE
  return (short)(r >> 16);
}
__device__ __forceinline__ float bf2f(short x) {
  union { unsigned u; float f; } v;
  v.u = ((unsigned)(unsigned short)x) << 16;
  return v.f;
}

// async global->LDS 16B: dest is wave-uniform base + lane*16 (m104/m108 caveat)
__device__ __forceinline__ void async16(const short* g, short* l) {
  __builtin_amdgcn_global_load_lds(
      (const __attribute__((address_space(1))) void*)(uintptr_t)(const void*)g,
      (__attribute__((address_space(3))) void*)(uintptr_t)(void*)l,
      16, 0, 0);
}

// ---------------- fp32 -> bf16 elementwise (x) ----------------
__global__ void cvt_bf16_kernel(const float* __restrict__ src, short* __restrict__ dst, int n4) {
  int t = blockIdx.x * blockDim.x + threadIdx.x;
  if (t >= n4) return;
  float4 v = ((const float4*)src)[t];
  short4 o;
  o.x = f2bf(v.x); o.y = f2bf(v.y); o.z = f2bf(v.z); o.w = f2bf(v.w);
  *(short4*)(dst + (size_t)t * 4) = o;
}

// ------- fp32 [Kdim][Ndim] -> bf16 transposed [Ndim][Kdim] (weights) -------
__global__ void wtrans_kernel(const float* __restrict__ src, short* __restrict__ dst,
                              int Kdim, int Ndim) {
  __shared__ float tile[32][33];
  int n0 = blockIdx.x * 32, k0 = blockIdx.y * 32;
  for (int r = threadIdx.y; r < 32; r += 8)
    tile[r][threadIdx.x] = src[(size_t)(k0 + r) * Ndim + n0 + threadIdx.x];
  __syncthreads();
  for (int r = threadIdx.y; r < 32; r += 8)
    dst[(size_t)(n0 + r) * Kdim + k0 + threadIdx.x] = f2bf(tile[threadIdx.x][r]);
}

// ---------------- m97-style GEMM: C[M][N] = A[M][K] @ Bt[N][K]^T ----------------
#define BM 128
#define BN 128
#define BK 32

template<int BF16OUT>
__global__ __launch_bounds__(256) void gemm_bt_kernel(const short* __restrict__ A,
    const short* __restrict__ Bt, void* __restrict__ Cv, int M, int N, int K) {
  __shared__ alignas(16) short As[BM * BK];
  __shared__ alignas(16) short Bs[BN * BK];
  const int tid  = threadIdx.x;
  const int wave = tid >> 6;
  const int lane = tid & 63;
  const int quad = lane >> 4;
  const int lr   = lane & 15;
  const int m0 = blockIdx.y * BM;
  const int n0 = blockIdx.x * BN;
  const int wm = (wave >> 1) * 64;
  const int wn = (wave & 1) * 64;

  f32x4 acc[4][4];
#pragma unroll
  for (int i = 0; i < 4; i++)
#pragma unroll
    for (int j = 0; j < 4; j++) acc[i][j] = (f32x4){0.f, 0.f, 0.f, 0.f};

  // 128x32 tile = 512 chunks of 8 bf16; thread covers chunks tid and tid+256
  const int r0 = tid >> 2,          c0 = (tid & 3) * 8;
  const int r1 = (tid + 256) >> 2,  c1 = (tid & 3) * 8;  // (tid+256)&3 == tid&3

  for (int kt = 0; kt < K; kt += BK) {
    const short* ga = A  + (size_t)m0 * K + kt;
    const short* gb = Bt + (size_t)n0 * K + kt;
    async16(ga + (size_t)r0 * K + c0, As + wave * 512);
    async16(ga + (size_t)r1 * K + c1, As + 2048 + wave * 512);
    async16(gb + (size_t)r0 * K + c0, Bs + wave * 512);
    async16(gb + (size_t)r1 * K + c1, Bs + 2048 + wave * 512);
    __syncthreads();   // drains vmcnt for global_load_lds

    short8 a[4], b[4];
#pragma unroll
    for (int i = 0; i < 4; i++) a[i] = *(const short8*)(As + (wm + i * 16 + lr) * BK + quad * 8);
#pragma unroll
    for (int j = 0; j < 4; j++) b[j] = *(const short8*)(Bs + (wn + j * 16 + lr) * BK + quad * 8);
#pragma unroll
    for (int i = 0; i < 4; i++)
#pragma unroll
      for (int j = 0; j < 4; j++)
        acc[i][j] = __builtin_amdgcn_mfma_f32_16x16x32_bf16(a[i], b[j], acc[i][j], 0, 0, 0);
    __syncthreads();   // reads done before next stage overwrites
  }

#pragma unroll
  for (int i = 0; i < 4; i++) {
    const int row = m0 + wm + i * 16 + quad * 4;
#pragma unroll
    for (int j = 0; j < 4; j++) {
      const int col = n0 + wn + j * 16 + lr;
#pragma unroll
      for (int r = 0; r < 4; r++) {
        float v = acc[i][j][r];
        if (BF16OUT) ((short*)Cv)[(size_t)(row + r) * N + col] = f2bf(v);
        else         ((float*)Cv)[(size_t)(row + r) * N + col] = v;
      }
    }
  }
}

// ---------------- RoPE + scatter into attention layouts ----------------
// QKVb [4096][3072] bf16 -> Qb [B][NH][S][HD] (scaled), Kb [B][NKV][S][HD]
__global__ void rope_kernel(const short* __restrict__ QKVb, short* __restrict__ Qb,
                            short* __restrict__ Kb) {
  const int head = blockIdx.y;                              // 0..19: 0..15=Q, 16..19=K
  const int t = blockIdx.x * blockDim.x + threadIdx.x;      // 0..4096*64-1
  const int i = t & 63;
  const int row = t >> 6;                                   // s*B + b
  const int s = row >> 1;
  const int b = row & 1;
  float inv_freq = expf(-(float)i * (1.0f / 64.0f) * 9.210340371976184f); // theta^(-i/64)
  float ang = (float)s * inv_freq;
  float sn, cs;
  sincosf(ang, &sn, &cs);
  if (head < NH) {
    const short* p = QKVb + (size_t)row * NQKV + head * HD;
    float v1 = bf2f(p[i]), v2 = bf2f(p[i + 64]);
    short* q = Qb + ((size_t)(b * NH + head) * S_LEN + s) * HD;
    q[i]      = f2bf((v1 * cs - v2 * sn) * SCALE);
    q[i + 64] = f2bf((v2 * cs + v1 * sn) * SCALE);
  } else {
    const int kv = head - NH;
    const short* p = QKVb + (size_t)row * NQKV + NH * HD + kv * HD;
    float v1 = bf2f(p[i]), v2 = bf2f(p[i + 64]);
    short* k = Kb + ((size_t)(b * NKV + kv) * S_LEN + s) * HD;
    k[i]      = f2bf(v1 * cs - v2 * sn);
    k[i + 64] = f2bf(v2 * cs + v1 * sn);
  }
}

// ---------------- V transpose: QKVb V-cols -> Vtb [B][NKV][HD][S] ----------------
__global__ void vtrans_kernel(const short* __restrict__ QKVb, short* __restrict__ Vtb) {
  __shared__ short tile[32][33];
  const int bz = blockIdx.z;               // b*NKV + kv
  const int b  = bz >> 2;
  const int s0 = blockIdx.x * 32;
  const int d0 = blockIdx.y * 32;
  const int vcol = NH * HD + NKV * HD + (bz & 3) * HD;   // 2560 + kv*128
  for (int r = threadIdx.y; r < 32; r += 8)
    tile[r][threadIdx.x] = QKVb[(size_t)((s0 + r) * B_SZ + b) * NQKV + vcol + d0 + threadIdx.x];
  __syncthreads();
  for (int r = threadIdx.y; r < 32; r += 8)
    Vtb[((size_t)bz * HD + d0 + r) * S_LEN + s0 + threadIdx.x] = tile[threadIdx.x][r];
}

// ---------------- flash attention (causal, online softmax) ----------------
// grid (S/64, B*NH), 256 thr. Wave w owns q-rows [q0+16w, q0+16w+16).
#define KLD 136   // Ks row pitch (pad: 272B = 68 dw -> 4-bank shift/row)
#define VLD 72    // Vs/Ps row pitch (144B = 36 dw)
__global__ __launch_bounds__(256) void attn_kernel(const short* __restrict__ Qb,
    const short* __restrict__ Kb, const short* __restrict__ Vtb, short* __restrict__ Ob) {
  __shared__ alignas(16) short Ks[64 * KLD];     // [kv][d]
  __shared__ alignas(16) short Vs[HD * VLD];     // [d][kv]
  __shared__ alignas(16) short Ps[4][16 * VLD];  // per-wave [q][kv]
  const int tid = threadIdx.x, wave = tid >> 6, lane = tid & 63;
  const int quad = lane >> 4, lr = lane & 15;
  const int qb = blockIdx.x;
  const int bh = blockIdx.y;
  const int b = bh >> 4, h = bh & 15;
  const int kvh = h >> 2;
  const int q0 = qb * 64;
  const int qw = q0 + wave * 16;

  // Q fragments (A-operand: m=lr, k=quad*8+j within 32-chunk c)
  const short* Qbase = Qb + ((size_t)bh * S_LEN + qw) * HD;
  short8 aq[4];
#pragma unroll
  for (int c = 0; c < 4; ++c)
    aq[c] = *(const short8*)(Qbase + lr * HD + c * 32 + quad * 8);

  f32x4 o[8];
#pragma unroll
  for (int n = 0; n < 8; ++n) o[n] = (f32x4){0.f, 0.f, 0.f, 0.f};
  float m_i[4], l_i[4];
#pragma unroll
  for (int r = 0; r < 4; ++r) { m_i[r] = -1e30f; l_i[r] = 0.f; }

  const short* Kbase = Kb  + (size_t)(b * NKV + kvh) * S_LEN * HD;
  const short* Vbase = Vtb + (size_t)(b * NKV + kvh) * HD * S_LEN;

  for (int kv0 = 0; kv0 <= q0; kv0 += 64) {
    __syncthreads();   // previous iter's LDS reads done
    {
      const short* gk = Kbase + (size_t)kv0 * HD;
      const short* gv = Vbase + kv0;
#pragma unroll
      for (int r = 0; r < 4; ++r) {
        int ck = tid + r * 256;                    // 1024 chunks of 8 bf16 each
        int krow = ck >> 4, kc = (ck & 15) * 8;    // K: 16 chunks/row of 128
        *(int4*)(Ks + krow * KLD + kc) = *(const int4*)(gk + (size_t)ck * 8);
        int d = ck >> 3, c8 = (ck & 7) * 8;        // Vt: 8 chunks/row of 64
        *(int4*)(Vs + d * VLD + c8) = *(const int4*)(gv + (size_t)d * S_LEN + c8);
      }
    }
    __syncthreads();

    // scores: 4 tiles of 16 kv, K-dim = HD in 4 chunks of 32
    f32x4 sc[4];
#pragma unroll
    for (int t = 0; t < 4; ++t) {
      sc[t] = (f32x4){0.f, 0.f, 0.f, 0.f};
#pragma unroll
      for (int c = 0; c < 4; ++c) {
        short8 bk = *(const short8*)(Ks + (t * 16 + lr) * KLD + c * 32 + quad * 8);
        sc[t] = __builtin_amdgcn_mfma_f32_16x16x32_bf16(aq[c], bk, sc[t], 0, 0, 0);
      }
    }
    // causal mask + block row-max (row = qw+quad*4+r, col = kv0+t*16+lr)
    float mb[4];
#pragma unroll
    for (int r = 0; r < 4; ++r) mb[r] = -3.0e38f;
#pragma unroll
    for (int t = 0; t < 4; ++t) {
      const int col = kv0 + t * 16 + lr;
#pragma unroll
      for (int r = 0; r < 4; ++r) {
        const int rowq = qw + quad * 4 + r;
        float sv = sc[t][r];
        sv = (col > rowq) ? -3.0e38f : sv;
        sc[t][r] = sv;
        mb[r] = fmaxf(mb[r], sv);
      }
    }
#pragma unroll
    for (int r = 0; r < 4; ++r)
      for (int off = 8; off > 0; off >>= 1)
        mb[r] = fmaxf(mb[r], __shfl_xor(mb[r], off, 16));

    float alpha[4], rsum[4];
#pragma unroll
    for (int r = 0; r < 4; ++r) {
      float mnew = fmaxf(m_i[r], mb[r]);
      alpha[r] = __expf(m_i[r] - mnew);
      m_i[r] = mnew;
      rsum[r] = 0.f;
    }
#pragma unroll
    for (int t = 0; t < 4; ++t)
#pragma unroll
      for (int r = 0; r < 4; ++r) {
        float p = __expf(sc[t][r] - m_i[r]);
        rsum[r] += p;
        Ps[wave][(quad * 4 + r) * VLD + t * 16 + lr] = f2bf(p);
      }
#pragma unroll
    for (int r = 0; r < 4; ++r) {
      for (int off = 8; off > 0; off >>= 1)
        rsum[r] += __shfl_xor(rsum[r], off, 16);
      l_i[r] = l_i[r] * alpha[r] + rsum[r];
    }
#pragma unroll
    for (int n = 0; n < 8; ++n)
#pragma unroll
      for (int r = 0; r < 4; ++r) o[n][r] *= alpha[r];
    __syncthreads();   // P visible (and orders vs next staging)

    // PV: o[n] += P(16x64) @ V(64x16), kv in 2 chunks of 32
    short8 ap[2];
#pragma unroll
    for (int c = 0; c < 2; ++c)
      ap[c] = *(const short8*)(&Ps[wave][lr * VLD + c * 32 + quad * 8]);
#pragma unroll
    for (int n = 0; n < 8; ++n) {
#pragma unroll
      for (int c = 0; c < 2; ++c) {
        short8 bv = *(const short8*)(Vs + (n * 16 + lr) * VLD + c * 32 + quad * 8);
        o[n] = __builtin_amdgcn_mfma_f32_16x16x32_bf16(ap[c], bv, o[n], 0, 0, 0);
      }
    }
  }

  // epilogue: Ob[(s*B+b)][h*HD + d]
#pragma unroll
  for (int r = 0; r < 4; ++r) {
    const int srow = qw + quad * 4 + r;
    const float invl = 1.0f / l_i[r];
    short* orow = Ob + (size_t)(srow * B_SZ + b) * D_MODEL + h * HD;
#pragma unroll
    for (int n = 0; n < 8; ++n)
      orow[n * 16 + lr] = f2bf(o[n][r] * invl);
  }
}

// ---------------- launch ----------------
extern "C" void kernel_launch(void* const* d_in, const int* in_sizes, int n_in,
                              void* d_out, int out_size, void* d_ws, size_t ws_size,
                              hipStream_t stream) {
  (void)in_sizes; (void)n_in; (void)out_size; (void)ws_size;
  const float* x  = (const float*)d_in[0];
  const float* Wq = (const float*)d_in[1];
  const float* Wk = (const float*)d_in[2];
  const float* Wv = (const float*)d_in[3];
  const float* Wo = (const float*)d_in[4];
  float* out = (float*)d_out;
  char* ws = (char*)d_ws;

  // region A [0, 29360128): Wqkv_t(12M)+xb(16M); later Qb(16M)+Kb(4M)+Vtb(4M)
  short* Wqkv_t = (short*)(ws);                    // [3072][2048]
  short* xb     = (short*)(ws + 12582912);         // [4096][2048]
  short* Qb     = (short*)(ws);                    // [2][16][2048][128]
  short* Kb     = (short*)(ws + 16777216);         // [2][4][2048][128]
  short* Vtb    = (short*)(ws + 20971520);         // [2][4][128][2048]
  // region B [29360128, 54525952): QKVb(24M); later Ob(16M)
  short* QKVb   = (short*)(ws + 29360128);         // [4096][3072]
  short* Ob     = (short*)(ws + 29360128);         // [4096][2048]
  // region C [54525952, 62914560): Wo_t(8M)
  short* Wo_t   = (short*)(ws + 54525952);         // [2048][2048]

  dim3 tblk(32, 8);

  // 1. x -> bf16
  cvt_bf16_kernel<<<(ROWS * D_MODEL / 4 + 255) / 256, 256, 0, stream>>>(x, xb, ROWS * D_MODEL / 4);
  // 2. weight transposes to B^T layout (bf16)
  wtrans_kernel<<<dim3(64, 64), tblk, 0, stream>>>(Wq, Wqkv_t,               2048, 2048);
  wtrans_kernel<<<dim3(16, 64), tblk, 0, stream>>>(Wk, Wqkv_t + 2048 * 2048, 2048,  512);
  wtrans_kernel<<<dim3(16, 64), tblk, 0, stream>>>(Wv, Wqkv_t + 2560 * 2048, 2048,  512);
  wtrans_kernel<<<dim3(64, 64), tblk, 0, stream>>>(Wo, Wo_t,                 2048, 2048);
  // 3. QKV projection (bf16 out)
  gemm_bt_kernel<1><<<dim3(NQKV / BN, ROWS / BM), 256, 0, stream>>>(xb, Wqkv_t, QKVb, ROWS, NQKV, D_MODEL);
  // 4. RoPE + scatter Q/K
  rope_kernel<<<dim3(1024, NH + NKV), 256, 0, stream>>>(QKVb, Qb, Kb);
  // 5. V transpose
  vtrans_kernel<<<dim3(S_LEN / 32, HD / 32, B_SZ * NKV), tblk, 0, stream>>>(QKVb, Vtb);
  // 6. causal flash attention
  attn_kernel<<<dim3(S_LEN / 64, B_SZ * NH), 256, 0, stream>>>(Qb, Kb, Vtb, Ob);
  // 7. output projection (fp32 out)
  gemm_bt_kernel<0><<<dim3(D_MODEL / BN, ROWS / BM), 256, 0, stream>>>(Ob, Wo_t, out, ROWS, D_MODEL, D_MODEL);
}